// Round 17
// baseline (188.019 us; speedup 1.0000x reference)
//
#include <hip/hip_runtime.h>
#include <hip/hip_bf16.h>
#include <cstdint>

#define S_ 2048
#define M_ 512
#define L_ 2560
#define D_ 1024
#define F_ 4096
#define H_ 16
#define DH_ 64
#define W_ 256
#define NR_ 513
#define NRP_ 640

typedef unsigned int uint32;
typedef __attribute__((ext_vector_type(8))) short bf16x8;
typedef __attribute__((ext_vector_type(4))) float f32x4;

__device__ __forceinline__ ushort f2bf(float f) {
  uint32 u = __builtin_bit_cast(uint32, f);
  u += 0x7FFFu + ((u >> 16) & 1u);
  return (ushort)(u >> 16);
}
__device__ __forceinline__ float bf2f(ushort s) {
  uint32 u = ((uint32)s) << 16;
  return __builtin_bit_cast(float, u);
}
__device__ __forceinline__ ushort4 pack4(float4 vf) {
  ushort4 r;
  r.x = f2bf(vf.x); r.y = f2bf(vf.y); r.z = f2bf(vf.z); r.w = f2bf(vf.w);
  return r;
}
__device__ __forceinline__ float gelu_tanh(float x) {
  float t = 0.7978845608028654f * x * (1.f + 0.044715f * x * x);
  float e = __expf(2.f * t);
  float th = 1.f - 2.f / (e + 1.f);
  return 0.5f * x * (1.f + th);
}

// async global(16B/lane) -> LDS, wave-uniform LDS base + lane*16
__device__ __forceinline__ void gld_lds16(const ushort* g, ushort* l) {
  __builtin_amdgcn_global_load_lds((const __attribute__((address_space(1))) void*)g,
                                   (__attribute__((address_space(3))) void*)l, 16, 0, 0);
}

// ================= fused prep: 7 weight transposes + kv pack + sinusoid =================
__device__ __forceinline__ void tr_tile(const float* __restrict__ in, ushort* __restrict__ out,
                                        int R, int C, int c0, int r0, int tid,
                                        float (*tile)[33]) {
  const int tx = tid & 31, ty = tid >> 5;
#pragma unroll
  for (int i = 0; i < 4; i++)
    tile[ty + i * 8][tx] = in[(size_t)(r0 + ty + i * 8) * C + c0 + tx];
  __syncthreads();
  const int cc = tid >> 3, rq = tid & 7;
  ushort4 o;
  o.x = f2bf(tile[rq * 4 + 0][cc]);
  o.y = f2bf(tile[rq * 4 + 1][cc]);
  o.z = f2bf(tile[rq * 4 + 2][cc]);
  o.w = f2bf(tile[rq * 4 + 3][cc]);
  *(ushort4*)(out + (size_t)(c0 + cc) * R + r0 + rq * 4) = o;
  __syncthreads();
}

__global__ __launch_bounds__(256)
void prep_kernel(const float* __restrict__ x, const float* __restrict__ mem,
                 const float* __restrict__ Wq, const float* __restrict__ Wk,
                 const float* __restrict__ Wv, const float* __restrict__ Wo,
                 const float* __restrict__ Wr, const float* __restrict__ W1,
                 const float* __restrict__ W2,
                 ushort* __restrict__ WqT, ushort* __restrict__ WkT,
                 ushort* __restrict__ WvT, ushort* __restrict__ WoT,
                 ushort* __restrict__ WrT, ushort* __restrict__ W1T,
                 ushort* __restrict__ W2T,
                 ushort* __restrict__ kvb, ushort* __restrict__ remb) {
  __shared__ float tile[32][33];
  const int bid = blockIdx.x;
  const int tid = threadIdx.x;

  if (bid < 5120) {
    const int which = bid >> 10, idx = bid & 1023;
    const float* ins[5] = {Wq, Wk, Wv, Wo, Wr};
    ushort* outs[5] = {WqT, WkT, WvT, WoT, WrT};
    tr_tile(ins[which], outs[which], 1024, 1024, (idx & 31) * 32, (idx >> 5) * 32, tid, tile);
  } else if (bid < 9216) {
    const int idx = bid - 5120;
    tr_tile(W1, W1T, 1024, 4096, (idx % 128) * 32, (idx / 128) * 32, tid, tile);
  } else if (bid < 13312) {
    const int idx = bid - 9216;
    tr_tile(W2, W2T, 4096, 1024, (idx & 31) * 32, (idx >> 5) * 32, tid, tile);
  } else if (bid < 15872) {
    const int k = (bid - 13312) * 256 + tid;
    const int l = k >> 8, c = k & 255;
    const float4* src = (l < M_) ? (const float4*)(mem + (size_t)l * D_)
                                 : (const float4*)(x + (size_t)(l - M_) * D_);
    ((ushort4*)kvb)[k] = pack4(src[c]);
  } else {
    const int idx = (bid - 15872) * 256 + tid;
    const int r = idx >> 9, f = idx & 511;
    if (r < NR_) {
      float invf = __expf(-(float)f * (9.210340371976184f / 512.0f));
      float ang = (float)(r - W_) * invf;
      remb[(size_t)r * D_ + f] = f2bf(__sinf(ang));
      remb[(size_t)r * D_ + 512 + f] = f2bf(__cosf(ang));
    } else if (r < NRP_) {
      remb[(size_t)r * D_ + f] = 0;
      remb[(size_t)r * D_ + 512 + f] = 0;
    }
  }
}

// ====== 8-phase 128x256 GEMM core (T2+T3+T4+T5) ======
template <int EPI, int SPLITK>
__device__ __forceinline__
void gemm8p2_core(const ushort* __restrict__ A, const ushort* __restrict__ BT,
                  void* __restrict__ Cout, void* __restrict__ Cout2,
                  void* __restrict__ Cout3, void* __restrict__ Cout4,
                  const float* __restrict__ bias, int Msz, int Nsz, int Ksz, int Kstride,
                  int gx, int bid, int nwg, char* dyn) {
  const int tid = threadIdx.x;
  const int wave = tid >> 6, lane = tid & 63;
  const int wr = wave >> 2, wc = wave & 3;
  const int fr = lane & 15, gf = lane >> 4;
  const int sl = fr & 7;

  const int xcd = bid & 7, idx = bid >> 3;
  const int q = nwg >> 3, r8 = nwg & 7;
  const int swz = (xcd < r8 ? xcd * (q + 1) : r8 * (q + 1) + (xcd - r8) * q) + idx;
  const int gy = Msz / 128;
  const int bx = swz % gx;
  const int rest = swz / gx;
  const int by = rest % gy;
  const int bz = rest / gy;
  const int brow = by * 128, bcol = bx * 256;
  const int koff = (SPLITK > 1) ? bz * Ksz : 0;

  const int nt = Ksz >> 6;

  const int srow = tid >> 3;
  const int scol = ((tid & 7) ^ (srow & 7)) * 8;
  const ushort* Ab = A + (size_t)(brow + srow) * Kstride + koff + scol;
  const ushort* Bb = BT + (size_t)(bcol + srow) * Kstride + koff + scol;

  auto stageA = [&](int t, int qm) {
    gld_lds16(Ab + (size_t)(qm * 64) * Kstride + t * 64,
              (ushort*)(dyn + (t & 1) * 49152 + qm * 8192) + wave * 512);
  };
  auto stageB = [&](int t, int qn) {
#pragma unroll
    for (int j = 0; j < 2; j++)
      gld_lds16(Bb + (size_t)(qn * 128 + j * 64) * Kstride + t * 64,
                (ushort*)(dyn + (t & 1) * 49152 + 16384 + qn * 16384 + j * 8192) + wave * 512);
  };

  const int ar0 = (wr * 32 + fr) * 128;
  const int ar1 = (wr * 32 + 16 + fr) * 128;
  const int br0 = (wc * 32 + fr) * 128;
  const int br1 = (wc * 32 + 16 + fr) * 128;
  const int s0 = (gf ^ sl) * 16;
  const int s1 = ((4 + gf) ^ sl) * 16;

  f32x4 acc00[2][2] = {}, acc01[2][2] = {}, acc10[2][2] = {}, acc11[2][2] = {};

  stageA(0, 0); stageB(0, 0); stageB(0, 1); stageA(0, 1);
  stageA(1, 0); stageB(1, 0);
  asm volatile("s_waitcnt vmcnt(3)" ::: "memory");
  __builtin_amdgcn_s_barrier();
  __builtin_amdgcn_sched_barrier(0);

#define PH4(QM, QN, ACC, STAGES, WAITS)                                                 \
  {                                                                                     \
    const char* ab = dyn + cur * 49152 + (QM) * 8192;                                   \
    const char* bb = dyn + cur * 49152 + 16384 + (QN) * 16384;                          \
    bf16x8 a00 = *(const bf16x8*)(ab + ar0 + s0);                                       \
    bf16x8 a10 = *(const bf16x8*)(ab + ar1 + s0);                                       \
    bf16x8 a01 = *(const bf16x8*)(ab + ar0 + s1);                                       \
    bf16x8 a11 = *(const bf16x8*)(ab + ar1 + s1);                                       \
    bf16x8 b00 = *(const bf16x8*)(bb + br0 + s0);                                       \
    bf16x8 b10 = *(const bf16x8*)(bb + br1 + s0);                                       \
    bf16x8 b01 = *(const bf16x8*)(bb + br0 + s1);                                       \
    bf16x8 b11 = *(const bf16x8*)(bb + br1 + s1);                                       \
    STAGES;                                                                             \
    WAITS;                                                                              \
    __builtin_amdgcn_s_barrier();                                                       \
    asm volatile("s_waitcnt lgkmcnt(0)" ::: "memory");                                  \
    __builtin_amdgcn_sched_barrier(0);                                                  \
    __builtin_amdgcn_s_setprio(1);                                                      \
    ACC[0][0] = __builtin_amdgcn_mfma_f32_16x16x32_bf16(a00, b00, ACC[0][0], 0, 0, 0);  \
    ACC[0][1] = __builtin_amdgcn_mfma_f32_16x16x32_bf16(a00, b10, ACC[0][1], 0, 0, 0);  \
    ACC[1][0] = __builtin_amdgcn_mfma_f32_16x16x32_bf16(a10, b00, ACC[1][0], 0, 0, 0);  \
    ACC[1][1] = __builtin_amdgcn_mfma_f32_16x16x32_bf16(a10, b10, ACC[1][1], 0, 0, 0);  \
    ACC[0][0] = __builtin_amdgcn_mfma_f32_16x16x32_bf16(a01, b01, ACC[0][0], 0, 0, 0);  \
    ACC[0][1] = __builtin_amdgcn_mfma_f32_16x16x32_bf16(a01, b11, ACC[0][1], 0, 0, 0);  \
    ACC[1][0] = __builtin_amdgcn_mfma_f32_16x16x32_bf16(a11, b01, ACC[1][0], 0, 0, 0);  \
    ACC[1][1] = __builtin_amdgcn_mfma_f32_16x16x32_bf16(a11, b11, ACC[1][1], 0, 0, 0);  \
    __builtin_amdgcn_s_setprio(0);                                                      \
    __builtin_amdgcn_s_barrier();                                                       \
  }

  for (int t = 0; t < nt; t++) {
    const int cur = t & 1;
    PH4(0, 0, acc00, { if (t + 1 < nt) stageB(t + 1, 1); }, {});
    PH4(0, 1, acc01, { if (t + 1 < nt) stageA(t + 1, 1); }, {});
    PH4(1, 0, acc10, { if (t + 2 < nt) stageA(t + 2, 0); }, {});
    PH4(1, 1, acc11, { if (t + 2 < nt) stageB(t + 2, 0); },
        {
          if (t + 1 < nt) {
            if (t + 2 < nt) asm volatile("s_waitcnt vmcnt(3)" ::: "memory");
            else            asm volatile("s_waitcnt vmcnt(0)" ::: "memory");
          }
        });
  }
#undef PH4

  const int r4 = gf * 4;
  float* co = (float*)Cout;
  bool addb = (EPI == 3);
  if constexpr (SPLITK >= 2) {
    if (bz == 1) { co = (float*)Cout2; addb = false; }
  }
  if constexpr (SPLITK == 4) {
    if (bz == 2) { co = (float*)Cout3; addb = false; }
    if (bz == 3) { co = (float*)Cout4; addb = false; }
  }
  auto wrq = [&](const f32x4 (&ACC)[2][2], int QM, int QN) {
#pragma unroll
    for (int m = 0; m < 2; m++) {
#pragma unroll
      for (int n = 0; n < 2; n++) {
        const int col = bcol + QN * 128 + wc * 32 + n * 16 + fr;
        const int row0 = brow + QM * 64 + wr * 32 + m * 16 + r4;
        if constexpr (EPI == 5) {
          if (col < 1024) {
#pragma unroll
            for (int r = 0; r < 4; r++)
              ((ushort*)Cout)[(size_t)(row0 + r) * 1024 + col] = f2bf(ACC[m][n][r]);
          } else {
            ushort4 pk;
            pk.x = f2bf(ACC[m][n][0]); pk.y = f2bf(ACC[m][n][1]);
            pk.z = f2bf(ACC[m][n][2]); pk.w = f2bf(ACC[m][n][3]);
            *(ushort4*)((ushort*)Cout2 + (size_t)(col - 1024) * Msz + row0) = pk;
          }
        } else if constexpr (EPI == 0 || EPI == 2) {
#pragma unroll
          for (int r = 0; r < 4; r++) {
            float val = ACC[m][n][r];
            size_t o = (size_t)(row0 + r) * Nsz + col;
            if constexpr (EPI == 2) ((ushort*)Cout)[o] = f2bf(gelu_tanh(val + bias[col]));
            else ((ushort*)Cout)[o] = f2bf(val);
          }
        } else {
#pragma unroll
          for (int r = 0; r < 4; r++) {
            float val = ACC[m][n][r];
            co[(size_t)(row0 + r) * Nsz + col] = addb ? val + bias[col] : val;
          }
        }
      }
    }
  };
  wrq(acc00, 0, 0);
  wrq(acc01, 0, 1);
  wrq(acc10, 1, 0);
  wrq(acc11, 1, 1);
}

template <int EPI, int SPLITK>
__global__ __launch_bounds__(512)
void gemm8p2_kern(const ushort* __restrict__ A, const ushort* __restrict__ BT,
                  void* __restrict__ Cout, void* __restrict__ Cout2,
                  void* __restrict__ Cout3, void* __restrict__ Cout4,
                  const float* __restrict__ bias, int Msz, int Nsz, int Ksz, int Kstride,
                  int gx) {
  extern __shared__ __align__(16) char dyn[];
  gemm8p2_core<EPI, SPLITK>(A, BT, Cout, Cout2, Cout3, Cout4, bias,
                            Msz, Nsz, Ksz, Kstride, gx, blockIdx.x, gridDim.x, dyn);
}

// merged Q / KV / R projection on the 8-phase core: 64 + 160 + 20 = 244 blocks
__global__ __launch_bounds__(512)
void proj8p(const ushort* __restrict__ kvb, const ushort* __restrict__ WqT,
            const ushort* __restrict__ WkvT, const ushort* __restrict__ WrT,
            const ushort* __restrict__ remb,
            ushort* __restrict__ qb, ushort* __restrict__ kb,
            ushort* __restrict__ Vt, ushort* __restrict__ Rb) {
  extern __shared__ __align__(16) char dyn[];
  const int bid = blockIdx.x;
  if (bid < 64) {
    gemm8p2_core<0, 1>(kvb + 512 * 1024, WqT, qb, nullptr, nullptr, nullptr, nullptr,
                       2048, 1024, 1024, 1024, 4, bid, 64, dyn);
  } else if (bid < 224) {
    gemm8p2_core<5, 1>(kvb, WkvT, kb, Vt, nullptr, nullptr, nullptr,
                       2560, 2048, 1024, 1024, 8, bid - 64, 160, dyn);
  } else {
    gemm8p2_core<0, 1>(remb, WrT, Rb, nullptr, nullptr, nullptr, nullptr,
                       640, 1024, 1024, 1024, 4, bid - 224, 20, dyn);
  }
}

// ---------------- banded attention v10: AC computed one chunk ahead ----------------
// Chunk c ends by computing AC(c+1) into scN (K prefetched 2 ahead, 3 K buffers);
// chunk c starts directly at the ring gather. Rotation period 6 (k%3, v/r%2).
__global__ __launch_bounds__(256)
void attn_mfma8(const ushort* __restrict__ qb, const ushort* __restrict__ kb,
                const ushort* __restrict__ Vt, const ushort* __restrict__ Rb,
                const float* __restrict__ ubias, const float* __restrict__ vbias,
                ushort* __restrict__ attb) {
  const int bid = blockIdx.x;
  const int swz = (bid & 7) * 64 + (bid >> 3);
  const int h = swz >> 5;
  const int i0 = (swz & 31) * 64;
  const int tid = threadIdx.x;
  const int wave = tid >> 6, lane = tid & 63;
  const int g = lane >> 4, fr = lane & 15;
  const int hD = h * DH_;

  __shared__ __align__(16) ushort ring[4][16][136];
  __shared__ __align__(16) ushort Pl[4][16][40];

  const int qi = i0 + wave * 16 + fr;
  bf16x8 afu[2], afv[2];
#pragma unroll
  for (int kst = 0; kst < 2; kst++) {
    const int dof = kst * 32 + g * 8;
    bf16x8 qv = *(const bf16x8*)(qb + (size_t)qi * D_ + hD + dof);
    const float* up = ubias + hD + dof;
    const float* vp = vbias + hD + dof;
    bf16x8 au, av;
#pragma unroll
    for (int j = 0; j < 8; j++) {
      float q = bf2f((ushort)qv[j]);
      au[j] = (short)f2bf(q + up[j]);
      av[j] = (short)f2bf(q + vp[j]);
    }
    afu[kst] = au; afv[kst] = av;
  }

  const int jb = 256 + i0;
  const int smax = 2303 - i0;
  const int sbase = wave * 16;

  auto produce = [&](int r0, bf16x8 rf0, bf16x8 rf1) {
    f32x4 acc = {};
    acc = __builtin_amdgcn_mfma_f32_16x16x32_bf16(afv[0], rf0, acc, 0, 0, 0);
    acc = __builtin_amdgcn_mfma_f32_16x16x32_bf16(afv[1], rf1, acc, 0, 0, 0);
#pragma unroll
    for (int rr = 0; rr < 4; rr++)
      ring[wave][g * 4 + rr][(r0 + fr) & 127] = f2bf(acc[rr]);
  };
  auto loadRrow = [&](int row, bf16x8* out0, bf16x8* out1) {
    const int rc = row < 0 ? 0 : row;
    *out0 = *(const bf16x8*)(Rb + (size_t)rc * D_ + hD + g * 8);
    *out1 = *(const bf16x8*)(Rb + (size_t)rc * D_ + hD + 32 + g * 8);
  };
  auto loadK = [&](int ch, bf16x8 (&kp)[2][2]) {
#pragma unroll
    for (int half = 0; half < 2; half++) {
      const int sa = sbase + ch * 32 + half * 16 + fr;
      const int jc = (jb + sa < L_ - 1) ? (jb + sa) : (L_ - 1);
      kp[half][0] = *(const bf16x8*)(kb + (size_t)jc * 1024 + hD + g * 8);
      kp[half][1] = *(const bf16x8*)(kb + (size_t)jc * 1024 + hD + 32 + g * 8);
    }
  };
  auto loadV = [&](int ch, bf16x8 (&vp)[4]) {
    int kc = jb + sbase + ch * 32 + g * 8;
    if (kc > L_ - 8) kc = L_ - 8;
#pragma unroll
    for (int n = 0; n < 4; n++)
      vp[n] = *(const bf16x8*)(Vt + (size_t)(hD + n * 16 + fr) * L_ + kc);
  };

  // prologue: ring tiles for chunk 0 (rows 480..527)
#pragma unroll
  for (int t = 0; t < 3; t++) {
    const int r0 = 480 + t * 16;
    bf16x8 rf0, rf1;
    loadRrow(r0 + fr, &rf0, &rf1);
    produce(r0, rf0, rf1);
  }

  float m4[4], l4[4];
  f32x4 oacc[4] = {};
#pragma unroll
  for (int rr = 0; rr < 4; rr++) { m4[rr] = -1e30f; l4[rr] = 0.f; }

  bf16x8 kA[2][2], kB[2][2], kC[2][2];
  bf16x8 vA[4], vB[4];
  bf16x8 rA[4], rB[4];
  f32x4 scN0 = {}, scN1 = {};

  loadRrow(448 + fr, &rA[0], &rA[1]);
  loadRrow(464 + fr, &rA[2], &rA[3]);
  loadK(0, kA); loadK(1, kB); loadV(0, vA);

  auto acpair = [&](bf16x8 (&kU)[2][2], f32x4* o0, f32x4* o1) {
    f32x4 a0 = {}, a1 = {};
    a0 = __builtin_amdgcn_mfma_f32_16x16x32_bf16(afu[0], kU[0][0], a0, 0, 0, 0);
    a0 = __builtin_amdgcn_mfma_f32_16x16x32_bf16(afu[1], kU[0][1], a0, 0, 0, 0);
    a1 = __builtin_amdgcn_mfma_f32_16x16x32_bf16(afu[0], kU[1][0], a1, 0, 0, 0);
    a1 = __builtin_amdgcn_mfma_f32_16x16x32_bf16(afu[1], kU[1][1], a1, 0, 0, 0);
    *o0 = a0; *o1 = a1;
  };

  auto body = [&](int ch, bf16x8 (&kU)[2][2], bf16x8 (&kN)[2][2], bf16x8 (&kN2)[2][2],
                  bf16x8 (&vU)[4], bf16x8 (&vP)[4],
                  bf16x8 (&rU)[4], bf16x8 (&rP)[4], bool first) -> bool {
    const int c0 = sbase + ch * 32;
    if (ch > 16 || c0 > smax) return false;
    f32x4 sc[2];
    if (first) {
      acpair(kU, &sc[0], &sc[1]);
    } else {
      sc[0] = scN0; sc[1] = scN1;
    }
    // prefetches
    if (ch + 2 <= 16) loadK(ch + 2, kN2);
    if (ch + 1 <= 16) loadV(ch + 1, vP);
    if (ch < 15) {
      loadRrow(416 - ch * 32 + fr, &rP[0], &rP[1]);
      loadRrow(432 - ch * 32 + fr, &rP[2], &rP[3]);
    }
    // BD gather + mask
#pragma unroll
    for (int half = 0; half < 2; half++) {
      const int rb2 = 512 + g * 4 - (ch * 32 + half * 16 + fr);
      const int sa = c0 + half * 16 + fr;
#pragma unroll
      for (int rr = 0; rr < 4; rr++) {
        const int r = rb2 + rr;
        const float bd = bf2f(ring[wave][g * 4 + rr][r & 127]);
        const bool valid = ((unsigned)r <= 512u) && (sa <= smax);
        sc[half][rr] = valid ? (sc[half][rr] + bd) * 0.125f : -1e30f;
      }
    }
    if (first) {
      f32x4 cm;
#pragma unroll
      for (int rr = 0; rr < 4; rr++) cm[rr] = fmaxf(sc[0][rr], sc[1][rr]);
#pragma unroll
      for (int off = 8; off; off >>= 1)
#pragma unroll
        for (int rr = 0; rr < 4; rr++) cm[rr] = fmaxf(cm[rr], __shfl_xor(cm[rr], off));
#pragma unroll
      for (int rr = 0; rr < 4; rr++) m4[rr] = cm[rr];
    } else {
      bool rise = false;
#pragma unroll
      for (int rr = 0; rr < 4; rr++)
        rise |= (fmaxf(sc[0][rr], sc[1][rr]) > m4[rr] + 8.f);
      if (__any(rise)) {
        f32x4 cm;
#pragma unroll
        for (int rr = 0; rr < 4; rr++) cm[rr] = fmaxf(sc[0][rr], sc[1][rr]);
#pragma unroll
        for (int off = 8; off; off >>= 1)
#pragma unroll
          for (int rr = 0; rr < 4; rr++) cm[rr] = fmaxf(cm[rr], __shfl_xor(cm[rr], off));
#pragma unroll
        for (int rr = 0; rr < 4; rr++) {
          const float nm = fmaxf(m4[rr], cm[rr]);
          const float esc = __expf(m4[rr] - nm);
          m4[rr] = nm;
          l4[rr] *= esc;
#pragma unroll
          for (int n = 0; n < 4; n++) oacc[n][rr] *= esc;
        }
      }
    }
    f32x4 pA, pB;
#pragma unroll
    for (int rr = 0; rr < 4; rr++) {
      pA[rr] = __expf(sc[0][rr] - m4[rr]);
      pB[rr] = __expf(sc[1][rr] - m4[rr]);
      l4[rr] += pA[rr] + pB[rr];
    }
#pragma unroll
    for (int rr = 0; rr < 4; rr++) {
      Pl[wave][g * 4 + rr][fr]      = f2bf(pA[rr]);
      Pl[wave][g * 4 + rr][16 + fr] = f2bf(pB[rr]);
    }
    bf16x8 pf = *(const bf16x8*)&Pl[wave][fr][g * 8];
    // produce ring tiles for ch+1 (latency filler for the pf read)
    if (ch < 16) {
      produce(448 - ch * 32, rU[0], rU[1]);
      produce(464 - ch * 32, rU[2], rU[3]);
      // AC for ch+1 (kN loaded >=1 chunk ago)
      acpair(kN, &scN0, &scN1);
    }
    // PV
#pragma unroll
    for (int n = 0; n < 4; n++)
      oacc[n] = __builtin_amdgcn_mfma_f32_16x16x32_bf16(pf, vU[n], oacc[n], 0, 0, 0);
    return true;
  };

  bool cont = body(0, kA, kB, kC, vA, vB, rA, rB, true);
  for (int base = 1; base <= 13 && cont; base += 6) {
    cont = body(base + 0, kB, kC, kA, vB, vA, rB, rA, false);
    if (cont) cont = body(base + 1, kC, kA, kB, vA, vB, rA, rB, false);
    if (cont) cont = body(base + 2, kA, kB, kC, vB, vA, rB, rA, false);
    if (cont) cont = body(base + 3, kB, kC, kA, vA, vB, rA, rB, false);
    if (cont) cont = body(base + 4, kC, kA, kB, vB, vA, rB, rA, false);
    if (cont) cont = body(base + 5, kA, kB, kC, vA, vB, rA, rB, false);
  }

#pragma unroll
  for (int off = 8; off; off >>= 1)
#pragma unroll
    for (int rr = 0; rr < 4; rr++) l4[rr] += __shfl_xor(l4[rr], off);
#pragma unroll
  for (int rr = 0; rr < 4; rr++) {
    const float inv = 1.f / l4[rr];
    const size_t rowo = (size_t)(i0 + sbase + g * 4 + rr) * D_ + hD;
#pragma unroll
    for (int n = 0; n < 4; n++)
      attb[rowo + n * 16 + fr] = f2bf(oacc[n][rr] * inv);
  }
}

// ---------------- residual + LayerNorm (2..5 addends) ----------------
__global__ __launch_bounds__(256)
void ln_kernel(const float* __restrict__ a, const float* __restrict__ b,
               const float* __restrict__ c, const float* __restrict__ d,
               const float* __restrict__ e,
               const float* __restrict__ gamma, const float* __restrict__ beta,
               float* __restrict__ outf, ushort* __restrict__ outb) {
  const int row = blockIdx.x;
  const int tid = threadIdx.x;
  const int wave = tid >> 6, lane = tid & 63;
  float4 va = ((const float4*)(a + (size_t)row * D_))[tid];
  float4 vb4 = ((const float4*)(b + (size_t)row * D_))[tid];
  float4 xv;
  xv.x = va.x + vb4.x; xv.y = va.y + vb4.y; xv.z = va.z + vb4.z; xv.w = va.w + vb4.w;
  if (c) {
    float4 vc = ((const float4*)(c + (size_t)row * D_))[tid];
    xv.x += vc.x; xv.y += vc.y; xv.z += vc.z; xv.w += vc.w;
  }
  if (d) {
    float4 vd = ((const float4*)(d + (size_t)row * D_))[tid];
    xv.x += vd.x; xv.y += vd.y; xv.z += vd.z; xv.w += vd.w;
  }
  if (e) {
    float4 ve = ((const float4*)(e + (size_t)row * D_))[tid];
    xv.x += ve.x; xv.y += ve.y; xv.z += ve.z; xv.w += ve.w;
  }
  float s = xv.x + xv.y + xv.z + xv.w;
  float q = xv.x * xv.x + xv.y * xv.y + xv.z * xv.z + xv.w * xv.w;
#pragma unroll
  for (int off = 32; off; off >>= 1) { s += __shfl_xor(s, off); q += __shfl_xor(q, off); }
  __shared__ float red[8];
  if (lane == 0) { red[wave * 2] = s; red[wave * 2 + 1] = q; }
  __syncthreads();
  float ts = red[0] + red[2] + red[4] + red[6];
  float tq = red[1] + red[3] + red[5] + red[7];
  float mu = ts * (1.f / D_);
  float var = tq * (1.f / D_) - mu * mu;
  float rs = rsqrtf(var + 1e-5f);
  float4 g4 = ((const float4*)gamma)[tid];
  float4 be4 = ((const float4*)beta)[tid];
  float4 y;
  y.x = (xv.x - mu) * rs * g4.x + be4.x;
  y.y = (xv.y - mu) * rs * g4.y + be4.y;
  y.z = (xv.z - mu) * rs * g4.z + be4.z;
  y.w = (xv.w - mu) * rs * g4.w + be4.w;
  ((float4*)(outf + (size_t)row * D_))[tid] = y;
  if (outb) ((ushort4*)(outb + (size_t)row * D_))[tid] = pack4(y);
}

extern "C" void kernel_launch(void* const* d_in, const int* in_sizes, int n_in,
                              void* d_out, int out_size, void* d_ws, size_t ws_size,
                              hipStream_t stream) {
  const float* x    = (const float*)d_in[0];
  const float* mem  = (const float*)d_in[1];
  const float* Wq   = (const float*)d_in[2];
  const float* Wk   = (const float*)d_in[3];
  const float* Wv   = (const float*)d_in[4];
  const float* Wo   = (const float*)d_in[5];
  const float* Wr   = (const float*)d_in[6];
  const float* u    = (const float*)d_in[7];
  const float* v    = (const float*)d_in[8];
  const float* ln1g = (const float*)d_in[9];
  const float* ln1b = (const float*)d_in[10];
  const float* W1   = (const float*)d_in[11];
  const float* b1   = (const float*)d_in[12];
  const float* W2   = (const float*)d_in[13];
  const float* b2   = (const float*)d_in[14];
  const float* ln2g = (const float*)d_in[15];
  const float* ln2b = (const float*)d_in[16];
  float* out = (float*)d_out;

  char* ws = (char*)d_ws;
  size_t off = 0;
  auto take = [&](size_t n) { char* p = ws + off; off += (n + 255) & ~(size_t)255; return p; };

  ushort* WqT = (ushort*)take(2097152);   // dead after proj -> FFN2 z2 partial
  ushort* WkT = (ushort*)take(2097152);   // WkT||WvT contiguous = [2048][1024]
  ushort* WvT = (ushort*)take(2097152);
  ushort* WoT = (ushort*)take(2097152);
  ushort* WrT = (ushort*)take(2097152);
  ushort* W1T = (ushort*)take(8388608);   // dead after FFN1 -> FFN2 z3 partial
  ushort* W2T = (ushort*)take(8388608);

  char* regA = take(8388608);             // kvb + remb; later reused for fbuf
  ushort* kvb  = (ushort*)regA;
  ushort* remb = (ushort*)(regA + 5242880);
  float*  fbuf = (float*)regA;            // FFN2 z0 (+bias)

  char* regB = take(20185088);            // qb,kb,Vt,Rb,attb; overlays: o2b, g
  ushort* qb   = (ushort*)regB;
  ushort* kb   = (ushort*)(regB + 4194304);
  ushort* Vt   = (ushort*)(regB + 9437184);
  ushort* Rb   = (ushort*)(regB + 14680064);
  ushort* attb = (ushort*)(regB + 15990784);
  float*  o2b  = (float*)regB;            // Wo z=1 partial
  ushort* g    = (ushort*)regB;           // FFN1 out

  float*  o2 = (float*)take(8388608);     // Wo z0; later FFN2 z1 partial
  float*  h  = (float*)take(8388608);
  ushort* hb = (ushort*)take(4194304);

  float* p2 = (float*)WqT;                // FFN2 z2 partial
  float* p3 = (float*)W1T;                // FFN2 z3 partial

  prep_kernel<<<17152, 256, 0, stream>>>(x, mem, Wq, Wk, Wv, Wo, Wr, W1, W2,
                                         WqT, WkT, WvT, WoT, WrT, W1T, W2T, kvb, remb);

  proj8p<<<244, 512, 98304, stream>>>(kvb, WqT, WkT, WrT, remb, qb, kb, Vt, Rb);

  attn_mfma8<<<512, 256, 0, stream>>>(qb, kb, Vt, Rb, u, v, attb);

  // Wo: 8-phase SK2, 128 blocks (z0->o2, z1->o2b)
  gemm8p2_kern<1, 2><<<128, 512, 98304, stream>>>(attb, WoT, o2, o2b, nullptr, nullptr,
                                                  nullptr, 2048, 1024, 512, 1024, 4);
  ln_kernel<<<2048, 256, 0, stream>>>(x, o2, o2b, nullptr, nullptr, ln1g, ln1b, h, hb);

  // FFN1: 8-phase 128x256, 256 blocks (full chip)
  gemm8p2_kern<2, 1><<<256, 512, 98304, stream>>>(hb, W1T, g, nullptr, nullptr, nullptr,
                                                  b1, 2048, 4096, 1024, 1024, 16);

  // FFN2: 8-phase SK4, 256 blocks (z0->fbuf(+b2), z1->o2, z2->p2, z3->p3)
  gemm8p2_kern<3, 4><<<256, 512, 98304, stream>>>(g, W2T, fbuf, o2, p2, p3,
                                                  b2, 2048, 1024, 1024, 4096, 4);
  ln_kernel<<<2048, 256, 0, stream>>>(h, fbuf, o2, p2, p3, ln2g, ln2b, out, nullptr);
}

// Round 18
// 187.205 us; speedup vs baseline: 1.0043x; 1.0043x over previous
//
#include <hip/hip_runtime.h>
#include <hip/hip_bf16.h>
#include <cstdint>

#define S_ 2048
#define M_ 512
#define L_ 2560
#define D_ 1024
#define F_ 4096
#define H_ 16
#define DH_ 64
#define W_ 256
#define NR_ 513
#define NRP_ 640

typedef unsigned int uint32;
typedef __attribute__((ext_vector_type(8))) short bf16x8;
typedef __attribute__((ext_vector_type(4))) float f32x4;

__device__ __forceinline__ ushort f2bf(float f) {
  uint32 u = __builtin_bit_cast(uint32, f);
  u += 0x7FFFu + ((u >> 16) & 1u);
  return (ushort)(u >> 16);
}
__device__ __forceinline__ float bf2f(ushort s) {
  uint32 u = ((uint32)s) << 16;
  return __builtin_bit_cast(float, u);
}
__device__ __forceinline__ ushort4 pack4(float4 vf) {
  ushort4 r;
  r.x = f2bf(vf.x); r.y = f2bf(vf.y); r.z = f2bf(vf.z); r.w = f2bf(vf.w);
  return r;
}
__device__ __forceinline__ float gelu_tanh(float x) {
  float t = 0.7978845608028654f * x * (1.f + 0.044715f * x * x);
  float e = __expf(2.f * t);
  float th = 1.f - 2.f / (e + 1.f);
  return 0.5f * x * (1.f + th);
}

// async global(16B/lane) -> LDS, wave-uniform LDS base + lane*16
__device__ __forceinline__ void gld_lds16(const ushort* g, ushort* l) {
  __builtin_amdgcn_global_load_lds((const __attribute__((address_space(1))) void*)g,
                                   (__attribute__((address_space(3))) void*)l, 16, 0, 0);
}

// ================= fused prep: 7 weight transposes + kv pack + sinusoid =================
__device__ __forceinline__ void tr_tile(const float* __restrict__ in, ushort* __restrict__ out,
                                        int R, int C, int c0, int r0, int tid,
                                        float (*tile)[33]) {
  const int tx = tid & 31, ty = tid >> 5;
#pragma unroll
  for (int i = 0; i < 4; i++)
    tile[ty + i * 8][tx] = in[(size_t)(r0 + ty + i * 8) * C + c0 + tx];
  __syncthreads();
  const int cc = tid >> 3, rq = tid & 7;
  ushort4 o;
  o.x = f2bf(tile[rq * 4 + 0][cc]);
  o.y = f2bf(tile[rq * 4 + 1][cc]);
  o.z = f2bf(tile[rq * 4 + 2][cc]);
  o.w = f2bf(tile[rq * 4 + 3][cc]);
  *(ushort4*)(out + (size_t)(c0 + cc) * R + r0 + rq * 4) = o;
  __syncthreads();
}

__global__ __launch_bounds__(256)
void prep_kernel(const float* __restrict__ x, const float* __restrict__ mem,
                 const float* __restrict__ Wq, const float* __restrict__ Wk,
                 const float* __restrict__ Wv, const float* __restrict__ Wo,
                 const float* __restrict__ Wr, const float* __restrict__ W1,
                 const float* __restrict__ W2,
                 ushort* __restrict__ WqT, ushort* __restrict__ WkT,
                 ushort* __restrict__ WvT, ushort* __restrict__ WoT,
                 ushort* __restrict__ WrT, ushort* __restrict__ W1T,
                 ushort* __restrict__ W2T,
                 ushort* __restrict__ kvb, ushort* __restrict__ remb) {
  __shared__ float tile[32][33];
  const int bid = blockIdx.x;
  const int tid = threadIdx.x;

  if (bid < 5120) {
    const int which = bid >> 10, idx = bid & 1023;
    const float* ins[5] = {Wq, Wk, Wv, Wo, Wr};
    ushort* outs[5] = {WqT, WkT, WvT, WoT, WrT};
    tr_tile(ins[which], outs[which], 1024, 1024, (idx & 31) * 32, (idx >> 5) * 32, tid, tile);
  } else if (bid < 9216) {
    const int idx = bid - 5120;
    tr_tile(W1, W1T, 1024, 4096, (idx % 128) * 32, (idx / 128) * 32, tid, tile);
  } else if (bid < 13312) {
    const int idx = bid - 9216;
    tr_tile(W2, W2T, 4096, 1024, (idx & 31) * 32, (idx >> 5) * 32, tid, tile);
  } else if (bid < 15872) {
    const int k = (bid - 13312) * 256 + tid;
    const int l = k >> 8, c = k & 255;
    const float4* src = (l < M_) ? (const float4*)(mem + (size_t)l * D_)
                                 : (const float4*)(x + (size_t)(l - M_) * D_);
    ((ushort4*)kvb)[k] = pack4(src[c]);
  } else {
    const int idx = (bid - 15872) * 256 + tid;
    const int r = idx >> 9, f = idx & 511;
    if (r < NR_) {
      float invf = __expf(-(float)f * (9.210340371976184f / 512.0f));
      float ang = (float)(r - W_) * invf;
      remb[(size_t)r * D_ + f] = f2bf(__sinf(ang));
      remb[(size_t)r * D_ + 512 + f] = f2bf(__cosf(ang));
    } else if (r < NRP_) {
      remb[(size_t)r * D_ + f] = 0;
      remb[(size_t)r * D_ + 512 + f] = 0;
    }
  }
}

// ====== 8-phase 128x256 GEMM core (T2+T3+T4+T5) ======
template <int EPI, int SPLITK>
__device__ __forceinline__
void gemm8p2_core(const ushort* __restrict__ A, const ushort* __restrict__ BT,
                  void* __restrict__ Cout, void* __restrict__ Cout2,
                  void* __restrict__ Cout3, void* __restrict__ Cout4,
                  const float* __restrict__ bias, int Msz, int Nsz, int Ksz, int Kstride,
                  int gx, int bid, int nwg, char* dyn) {
  const int tid = threadIdx.x;
  const int wave = tid >> 6, lane = tid & 63;
  const int wr = wave >> 2, wc = wave & 3;
  const int fr = lane & 15, gf = lane >> 4;
  const int sl = fr & 7;

  const int xcd = bid & 7, idx = bid >> 3;
  const int q = nwg >> 3, r8 = nwg & 7;
  const int swz = (xcd < r8 ? xcd * (q + 1) : r8 * (q + 1) + (xcd - r8) * q) + idx;
  const int gy = Msz / 128;
  const int bx = swz % gx;
  const int rest = swz / gx;
  const int by = rest % gy;
  const int bz = rest / gy;
  const int brow = by * 128, bcol = bx * 256;
  const int koff = (SPLITK > 1) ? bz * Ksz : 0;

  const int nt = Ksz >> 6;

  const int srow = tid >> 3;
  const int scol = ((tid & 7) ^ (srow & 7)) * 8;
  const ushort* Ab = A + (size_t)(brow + srow) * Kstride + koff + scol;
  const ushort* Bb = BT + (size_t)(bcol + srow) * Kstride + koff + scol;

  auto stageA = [&](int t, int qm) {
    gld_lds16(Ab + (size_t)(qm * 64) * Kstride + t * 64,
              (ushort*)(dyn + (t & 1) * 49152 + qm * 8192) + wave * 512);
  };
  auto stageB = [&](int t, int qn) {
#pragma unroll
    for (int j = 0; j < 2; j++)
      gld_lds16(Bb + (size_t)(qn * 128 + j * 64) * Kstride + t * 64,
                (ushort*)(dyn + (t & 1) * 49152 + 16384 + qn * 16384 + j * 8192) + wave * 512);
  };

  const int ar0 = (wr * 32 + fr) * 128;
  const int ar1 = (wr * 32 + 16 + fr) * 128;
  const int br0 = (wc * 32 + fr) * 128;
  const int br1 = (wc * 32 + 16 + fr) * 128;
  const int s0 = (gf ^ sl) * 16;
  const int s1 = ((4 + gf) ^ sl) * 16;

  f32x4 acc00[2][2] = {}, acc01[2][2] = {}, acc10[2][2] = {}, acc11[2][2] = {};

  stageA(0, 0); stageB(0, 0); stageB(0, 1); stageA(0, 1);
  stageA(1, 0); stageB(1, 0);
  asm volatile("s_waitcnt vmcnt(3)" ::: "memory");
  __builtin_amdgcn_s_barrier();
  __builtin_amdgcn_sched_barrier(0);

#define PH4(QM, QN, ACC, STAGES, WAITS)                                                 \
  {                                                                                     \
    const char* ab = dyn + cur * 49152 + (QM) * 8192;                                   \
    const char* bb = dyn + cur * 49152 + 16384 + (QN) * 16384;                          \
    bf16x8 a00 = *(const bf16x8*)(ab + ar0 + s0);                                       \
    bf16x8 a10 = *(const bf16x8*)(ab + ar1 + s0);                                       \
    bf16x8 a01 = *(const bf16x8*)(ab + ar0 + s1);                                       \
    bf16x8 a11 = *(const bf16x8*)(ab + ar1 + s1);                                       \
    bf16x8 b00 = *(const bf16x8*)(bb + br0 + s0);                                       \
    bf16x8 b10 = *(const bf16x8*)(bb + br1 + s0);                                       \
    bf16x8 b01 = *(const bf16x8*)(bb + br0 + s1);                                       \
    bf16x8 b11 = *(const bf16x8*)(bb + br1 + s1);                                       \
    STAGES;                                                                             \
    WAITS;                                                                              \
    __builtin_amdgcn_s_barrier();                                                       \
    asm volatile("s_waitcnt lgkmcnt(0)" ::: "memory");                                  \
    __builtin_amdgcn_sched_barrier(0);                                                  \
    __builtin_amdgcn_s_setprio(1);                                                      \
    ACC[0][0] = __builtin_amdgcn_mfma_f32_16x16x32_bf16(a00, b00, ACC[0][0], 0, 0, 0);  \
    ACC[0][1] = __builtin_amdgcn_mfma_f32_16x16x32_bf16(a00, b10, ACC[0][1], 0, 0, 0);  \
    ACC[1][0] = __builtin_amdgcn_mfma_f32_16x16x32_bf16(a10, b00, ACC[1][0], 0, 0, 0);  \
    ACC[1][1] = __builtin_amdgcn_mfma_f32_16x16x32_bf16(a10, b10, ACC[1][1], 0, 0, 0);  \
    ACC[0][0] = __builtin_amdgcn_mfma_f32_16x16x32_bf16(a01, b01, ACC[0][0], 0, 0, 0);  \
    ACC[0][1] = __builtin_amdgcn_mfma_f32_16x16x32_bf16(a01, b11, ACC[0][1], 0, 0, 0);  \
    ACC[1][0] = __builtin_amdgcn_mfma_f32_16x16x32_bf16(a11, b01, ACC[1][0], 0, 0, 0);  \
    ACC[1][1] = __builtin_amdgcn_mfma_f32_16x16x32_bf16(a11, b11, ACC[1][1], 0, 0, 0);  \
    __builtin_amdgcn_s_setprio(0);                                                      \
    __builtin_amdgcn_s_barrier();                                                       \
  }

  for (int t = 0; t < nt; t++) {
    const int cur = t & 1;
    PH4(0, 0, acc00, { if (t + 1 < nt) stageB(t + 1, 1); }, {});
    PH4(0, 1, acc01, { if (t + 1 < nt) stageA(t + 1, 1); }, {});
    PH4(1, 0, acc10, { if (t + 2 < nt) stageA(t + 2, 0); }, {});
    PH4(1, 1, acc11, { if (t + 2 < nt) stageB(t + 2, 0); },
        {
          if (t + 1 < nt) {
            if (t + 2 < nt) asm volatile("s_waitcnt vmcnt(3)" ::: "memory");
            else            asm volatile("s_waitcnt vmcnt(0)" ::: "memory");
          }
        });
  }
#undef PH4

  const int r4 = gf * 4;
  float* co = (float*)Cout;
  bool addb = (EPI == 3);
  if constexpr (SPLITK >= 2) {
    if (bz == 1) { co = (float*)Cout2; addb = false; }
  }
  if constexpr (SPLITK == 4) {
    if (bz == 2) { co = (float*)Cout3; addb = false; }
    if (bz == 3) { co = (float*)Cout4; addb = false; }
  }
  auto wrq = [&](const f32x4 (&ACC)[2][2], int QM, int QN) {
#pragma unroll
    for (int m = 0; m < 2; m++) {
#pragma unroll
      for (int n = 0; n < 2; n++) {
        const int col = bcol + QN * 128 + wc * 32 + n * 16 + fr;
        const int row0 = brow + QM * 64 + wr * 32 + m * 16 + r4;
        if constexpr (EPI == 5) {
          if (col < 1024) {
#pragma unroll
            for (int r = 0; r < 4; r++)
              ((ushort*)Cout)[(size_t)(row0 + r) * 1024 + col] = f2bf(ACC[m][n][r]);
          } else {
            ushort4 pk;
            pk.x = f2bf(ACC[m][n][0]); pk.y = f2bf(ACC[m][n][1]);
            pk.z = f2bf(ACC[m][n][2]); pk.w = f2bf(ACC[m][n][3]);
            *(ushort4*)((ushort*)Cout2 + (size_t)(col - 1024) * Msz + row0) = pk;
          }
        } else if constexpr (EPI == 0 || EPI == 2) {
#pragma unroll
          for (int r = 0; r < 4; r++) {
            float val = ACC[m][n][r];
            size_t o = (size_t)(row0 + r) * Nsz + col;
            if constexpr (EPI == 2) ((ushort*)Cout)[o] = f2bf(gelu_tanh(val + bias[col]));
            else ((ushort*)Cout)[o] = f2bf(val);
          }
        } else {
#pragma unroll
          for (int r = 0; r < 4; r++) {
            float val = ACC[m][n][r];
            co[(size_t)(row0 + r) * Nsz + col] = addb ? val + bias[col] : val;
          }
        }
      }
    }
  };
  wrq(acc00, 0, 0);
  wrq(acc01, 0, 1);
  wrq(acc10, 1, 0);
  wrq(acc11, 1, 1);
}

template <int EPI, int SPLITK>
__global__ __launch_bounds__(512)
void gemm8p2_kern(const ushort* __restrict__ A, const ushort* __restrict__ BT,
                  void* __restrict__ Cout, void* __restrict__ Cout2,
                  void* __restrict__ Cout3, void* __restrict__ Cout4,
                  const float* __restrict__ bias, int Msz, int Nsz, int Ksz, int Kstride,
                  int gx) {
  extern __shared__ __align__(16) char dyn[];
  gemm8p2_core<EPI, SPLITK>(A, BT, Cout, Cout2, Cout3, Cout4, bias,
                            Msz, Nsz, Ksz, Kstride, gx, blockIdx.x, gridDim.x, dyn);
}

// merged Q / KV / R projection on the 8-phase core: 64 + 160 + 20 = 244 blocks
__global__ __launch_bounds__(512)
void proj8p(const ushort* __restrict__ kvb, const ushort* __restrict__ WqT,
            const ushort* __restrict__ WkvT, const ushort* __restrict__ WrT,
            const ushort* __restrict__ remb,
            ushort* __restrict__ qb, ushort* __restrict__ kb,
            ushort* __restrict__ Vt, ushort* __restrict__ Rb) {
  extern __shared__ __align__(16) char dyn[];
  const int bid = blockIdx.x;
  if (bid < 64) {
    gemm8p2_core<0, 1>(kvb + 512 * 1024, WqT, qb, nullptr, nullptr, nullptr, nullptr,
                       2048, 1024, 1024, 1024, 4, bid, 64, dyn);
  } else if (bid < 224) {
    gemm8p2_core<5, 1>(kvb, WkvT, kb, Vt, nullptr, nullptr, nullptr,
                       2560, 2048, 1024, 1024, 8, bid - 64, 160, dyn);
  } else {
    gemm8p2_core<0, 1>(remb, WrT, Rb, nullptr, nullptr, nullptr, nullptr,
                       640, 1024, 1024, 1024, 4, bid - 224, 20, dyn);
  }
}

// ---------------- banded attention v10: AC computed one chunk ahead ----------------
// Chunk c ends by computing AC(c+1) into scN (K prefetched 2 ahead, 3 K buffers);
// chunk c starts directly at the ring gather. Rotation period 6 (k%3, v/r%2).
__global__ __launch_bounds__(256)
void attn_mfma8(const ushort* __restrict__ qb, const ushort* __restrict__ kb,
                const ushort* __restrict__ Vt, const ushort* __restrict__ Rb,
                const float* __restrict__ ubias, const float* __restrict__ vbias,
                ushort* __restrict__ attb) {
  const int bid = blockIdx.x;
  const int swz = (bid & 7) * 64 + (bid >> 3);
  const int h = swz >> 5;
  const int i0 = (swz & 31) * 64;
  const int tid = threadIdx.x;
  const int wave = tid >> 6, lane = tid & 63;
  const int g = lane >> 4, fr = lane & 15;
  const int hD = h * DH_;

  __shared__ __align__(16) ushort ring[4][16][136];
  __shared__ __align__(16) ushort Pl[4][16][40];

  const int qi = i0 + wave * 16 + fr;
  bf16x8 afu[2], afv[2];
#pragma unroll
  for (int kst = 0; kst < 2; kst++) {
    const int dof = kst * 32 + g * 8;
    bf16x8 qv = *(const bf16x8*)(qb + (size_t)qi * D_ + hD + dof);
    const float* up = ubias + hD + dof;
    const float* vp = vbias + hD + dof;
    bf16x8 au, av;
#pragma unroll
    for (int j = 0; j < 8; j++) {
      float q = bf2f((ushort)qv[j]);
      au[j] = (short)f2bf(q + up[j]);
      av[j] = (short)f2bf(q + vp[j]);
    }
    afu[kst] = au; afv[kst] = av;
  }

  const int jb = 256 + i0;
  const int smax = 2303 - i0;
  const int sbase = wave * 16;

  auto produce = [&](int r0, bf16x8 rf0, bf16x8 rf1) {
    f32x4 acc = {};
    acc = __builtin_amdgcn_mfma_f32_16x16x32_bf16(afv[0], rf0, acc, 0, 0, 0);
    acc = __builtin_amdgcn_mfma_f32_16x16x32_bf16(afv[1], rf1, acc, 0, 0, 0);
#pragma unroll
    for (int rr = 0; rr < 4; rr++)
      ring[wave][g * 4 + rr][(r0 + fr) & 127] = f2bf(acc[rr]);
  };
  auto loadRrow = [&](int row, bf16x8* out0, bf16x8* out1) {
    const int rc = row < 0 ? 0 : row;
    *out0 = *(const bf16x8*)(Rb + (size_t)rc * D_ + hD + g * 8);
    *out1 = *(const bf16x8*)(Rb + (size_t)rc * D_ + hD + 32 + g * 8);
  };
  auto loadK = [&](int ch, bf16x8 (&kp)[2][2]) {
#pragma unroll
    for (int half = 0; half < 2; half++) {
      const int sa = sbase + ch * 32 + half * 16 + fr;
      const int jc = (jb + sa < L_ - 1) ? (jb + sa) : (L_ - 1);
      kp[half][0] = *(const bf16x8*)(kb + (size_t)jc * 1024 + hD + g * 8);
      kp[half][1] = *(const bf16x8*)(kb + (size_t)jc * 1024 + hD + 32 + g * 8);
    }
  };
  auto loadV = [&](int ch, bf16x8 (&vp)[4]) {
    int kc = jb + sbase + ch * 32 + g * 8;
    if (kc > L_ - 8) kc = L_ - 8;
#pragma unroll
    for (int n = 0; n < 4; n++)
      vp[n] = *(const bf16x8*)(Vt + (size_t)(hD + n * 16 + fr) * L_ + kc);
  };

  // prologue: ring tiles for chunk 0 (rows 480..527)
#pragma unroll
  for (int t = 0; t < 3; t++) {
    const int r0 = 480 + t * 16;
    bf16x8 rf0, rf1;
    loadRrow(r0 + fr, &rf0, &rf1);
    produce(r0, rf0, rf1);
  }

  float m4[4], l4[4];
  f32x4 oacc[4] = {};
#pragma unroll
  for (int rr = 0; rr < 4; rr++) { m4[rr] = -1e30f; l4[rr] = 0.f; }

  bf16x8 kA[2][2], kB[2][2], kC[2][2];
  bf16x8 vA[4], vB[4];
  bf16x8 rA[4], rB[4];
  f32x4 scN0 = {}, scN1 = {};

  loadRrow(448 + fr, &rA[0], &rA[1]);
  loadRrow(464 + fr, &rA[2], &rA[3]);
  loadK(0, kA); loadK(1, kB); loadV(0, vA);

  auto acpair = [&](bf16x8 (&kU)[2][2], f32x4* o0, f32x4* o1) {
    f32x4 a0 = {}, a1 = {};
    a0 = __builtin_amdgcn_mfma_f32_16x16x32_bf16(afu[0], kU[0][0], a0, 0, 0, 0);
    a0 = __builtin_amdgcn_mfma_f32_16x16x32_bf16(afu[1], kU[0][1], a0, 0, 0, 0);
    a1 = __builtin_amdgcn_mfma_f32_16x16x32_bf16(afu[0], kU[1][0], a1, 0, 0, 0);
    a1 = __builtin_amdgcn_mfma_f32_16x16x32_bf16(afu[1], kU[1][1], a1, 0, 0, 0);
    *o0 = a0; *o1 = a1;
  };

  auto body = [&](int ch, bf16x8 (&kU)[2][2], bf16x8 (&kN)[2][2], bf16x8 (&kN2)[2][2],
                  bf16x8 (&vU)[4], bf16x8 (&vP)[4],
                  bf16x8 (&rU)[4], bf16x8 (&rP)[4], bool first) -> bool {
    const int c0 = sbase + ch * 32;
    if (ch > 16 || c0 > smax) return false;
    f32x4 sc[2];
    if (first) {
      acpair(kU, &sc[0], &sc[1]);
    } else {
      sc[0] = scN0; sc[1] = scN1;
    }
    // prefetches
    if (ch + 2 <= 16) loadK(ch + 2, kN2);
    if (ch + 1 <= 16) loadV(ch + 1, vP);
    if (ch < 15) {
      loadRrow(416 - ch * 32 + fr, &rP[0], &rP[1]);
      loadRrow(432 - ch * 32 + fr, &rP[2], &rP[3]);
    }
    // BD gather + mask
#pragma unroll
    for (int half = 0; half < 2; half++) {
      const int rb2 = 512 + g * 4 - (ch * 32 + half * 16 + fr);
      const int sa = c0 + half * 16 + fr;
#pragma unroll
      for (int rr = 0; rr < 4; rr++) {
        const int r = rb2 + rr;
        const float bd = bf2f(ring[wave][g * 4 + rr][r & 127]);
        const bool valid = ((unsigned)r <= 512u) && (sa <= smax);
        sc[half][rr] = valid ? (sc[half][rr] + bd) * 0.125f : -1e30f;
      }
    }
    if (first) {
      f32x4 cm;
#pragma unroll
      for (int rr = 0; rr < 4; rr++) cm[rr] = fmaxf(sc[0][rr], sc[1][rr]);
#pragma unroll
      for (int off = 8; off; off >>= 1)
#pragma unroll
        for (int rr = 0; rr < 4; rr++) cm[rr] = fmaxf(cm[rr], __shfl_xor(cm[rr], off));
#pragma unroll
      for (int rr = 0; rr < 4; rr++) m4[rr] = cm[rr];
    } else {
      bool rise = false;
#pragma unroll
      for (int rr = 0; rr < 4; rr++)
        rise |= (fmaxf(sc[0][rr], sc[1][rr]) > m4[rr] + 8.f);
      if (__any(rise)) {
        f32x4 cm;
#pragma unroll
        for (int rr = 0; rr < 4; rr++) cm[rr] = fmaxf(sc[0][rr], sc[1][rr]);
#pragma unroll
        for (int off = 8; off; off >>= 1)
#pragma unroll
          for (int rr = 0; rr < 4; rr++) cm[rr] = fmaxf(cm[rr], __shfl_xor(cm[rr], off));
#pragma unroll
        for (int rr = 0; rr < 4; rr++) {
          const float nm = fmaxf(m4[rr], cm[rr]);
          const float esc = __expf(m4[rr] - nm);
          m4[rr] = nm;
          l4[rr] *= esc;
#pragma unroll
          for (int n = 0; n < 4; n++) oacc[n][rr] *= esc;
        }
      }
    }
    f32x4 pA, pB;
#pragma unroll
    for (int rr = 0; rr < 4; rr++) {
      pA[rr] = __expf(sc[0][rr] - m4[rr]);
      pB[rr] = __expf(sc[1][rr] - m4[rr]);
      l4[rr] += pA[rr] + pB[rr];
    }
#pragma unroll
    for (int rr = 0; rr < 4; rr++) {
      Pl[wave][g * 4 + rr][fr]      = f2bf(pA[rr]);
      Pl[wave][g * 4 + rr][16 + fr] = f2bf(pB[rr]);
    }
    bf16x8 pf = *(const bf16x8*)&Pl[wave][fr][g * 8];
    // produce ring tiles for ch+1 (latency filler for the pf read)
    if (ch < 16) {
      produce(448 - ch * 32, rU[0], rU[1]);
      produce(464 - ch * 32, rU[2], rU[3]);
      // AC for ch+1 (kN loaded >=1 chunk ago)
      acpair(kN, &scN0, &scN1);
    }
    // PV
#pragma unroll
    for (int n = 0; n < 4; n++)
      oacc[n] = __builtin_amdgcn_mfma_f32_16x16x32_bf16(pf, vU[n], oacc[n], 0, 0, 0);
    return true;
  };

  bool cont = body(0, kA, kB, kC, vA, vB, rA, rB, true);
  for (int base = 1; base <= 13 && cont; base += 6) {
    cont = body(base + 0, kB, kC, kA, vB, vA, rB, rA, false);
    if (cont) cont = body(base + 1, kC, kA, kB, vA, vB, rA, rB, false);
    if (cont) cont = body(base + 2, kA, kB, kC, vB, vA, rB, rA, false);
    if (cont) cont = body(base + 3, kB, kC, kA, vA, vB, rA, rB, false);
    if (cont) cont = body(base + 4, kC, kA, kB, vB, vA, rB, rA, false);
    if (cont) cont = body(base + 5, kA, kB, kC, vA, vB, rA, rB, false);
  }

#pragma unroll
  for (int off = 8; off; off >>= 1)
#pragma unroll
    for (int rr = 0; rr < 4; rr++) l4[rr] += __shfl_xor(l4[rr], off);
#pragma unroll
  for (int rr = 0; rr < 4; rr++) {
    const float inv = 1.f / l4[rr];
    const size_t rowo = (size_t)(i0 + sbase + g * 4 + rr) * D_ + hD;
#pragma unroll
    for (int n = 0; n < 4; n++)
      attb[rowo + n * 16 + fr] = f2bf(oacc[n][rr] * inv);
  }
}

// ---------------- residual + LayerNorm (2..5 addends) ----------------
__global__ __launch_bounds__(256)
void ln_kernel(const float* __restrict__ a, const float* __restrict__ b,
               const float* __restrict__ c, const float* __restrict__ d,
               const float* __restrict__ e,
               const float* __restrict__ gamma, const float* __restrict__ beta,
               float* __restrict__ outf, ushort* __restrict__ outb) {
  const int row = blockIdx.x;
  const int tid = threadIdx.x;
  const int wave = tid >> 6, lane = tid & 63;
  float4 va = ((const float4*)(a + (size_t)row * D_))[tid];
  float4 vb4 = ((const float4*)(b + (size_t)row * D_))[tid];
  float4 xv;
  xv.x = va.x + vb4.x; xv.y = va.y + vb4.y; xv.z = va.z + vb4.z; xv.w = va.w + vb4.w;
  if (c) {
    float4 vc = ((const float4*)(c + (size_t)row * D_))[tid];
    xv.x += vc.x; xv.y += vc.y; xv.z += vc.z; xv.w += vc.w;
  }
  if (d) {
    float4 vd = ((const float4*)(d + (size_t)row * D_))[tid];
    xv.x += vd.x; xv.y += vd.y; xv.z += vd.z; xv.w += vd.w;
  }
  if (e) {
    float4 ve = ((const float4*)(e + (size_t)row * D_))[tid];
    xv.x += ve.x; xv.y += ve.y; xv.z += ve.z; xv.w += ve.w;
  }
  float s = xv.x + xv.y + xv.z + xv.w;
  float q = xv.x * xv.x + xv.y * xv.y + xv.z * xv.z + xv.w * xv.w;
#pragma unroll
  for (int off = 32; off; off >>= 1) { s += __shfl_xor(s, off); q += __shfl_xor(q, off); }
  __shared__ float red[8];
  if (lane == 0) { red[wave * 2] = s; red[wave * 2 + 1] = q; }
  __syncthreads();
  float ts = red[0] + red[2] + red[4] + red[6];
  float tq = red[1] + red[3] + red[5] + red[7];
  float mu = ts * (1.f / D_);
  float var = tq * (1.f / D_) - mu * mu;
  float rs = rsqrtf(var + 1e-5f);
  float4 g4 = ((const float4*)gamma)[tid];
  float4 be4 = ((const float4*)beta)[tid];
  float4 y;
  y.x = (xv.x - mu) * rs * g4.x + be4.x;
  y.y = (xv.y - mu) * rs * g4.y + be4.y;
  y.z = (xv.z - mu) * rs * g4.z + be4.z;
  y.w = (xv.w - mu) * rs * g4.w + be4.w;
  ((float4*)(outf + (size_t)row * D_))[tid] = y;
  if (outb) ((ushort4*)(outb + (size_t)row * D_))[tid] = pack4(y);
}

extern "C" void kernel_launch(void* const* d_in, const int* in_sizes, int n_in,
                              void* d_out, int out_size, void* d_ws, size_t ws_size,
                              hipStream_t stream) {
  const float* x    = (const float*)d_in[0];
  const float* mem  = (const float*)d_in[1];
  const float* Wq   = (const float*)d_in[2];
  const float* Wk   = (const float*)d_in[3];
  const float* Wv   = (const float*)d_in[4];
  const float* Wo   = (const float*)d_in[5];
  const float* Wr   = (const float*)d_in[6];
  const float* u    = (const float*)d_in[7];
  const float* v    = (const float*)d_in[8];
  const float* ln1g = (const float*)d_in[9];
  const float* ln1b = (const float*)d_in[10];
  const float* W1   = (const float*)d_in[11];
  const float* b1   = (const float*)d_in[12];
  const float* W2   = (const float*)d_in[13];
  const float* b2   = (const float*)d_in[14];
  const float* ln2g = (const float*)d_in[15];
  const float* ln2b = (const float*)d_in[16];
  float* out = (float*)d_out;

  char* ws = (char*)d_ws;
  size_t off = 0;
  auto take = [&](size_t n) { char* p = ws + off; off += (n + 255) & ~(size_t)255; return p; };

  ushort* WqT = (ushort*)take(2097152);   // dead after proj -> FFN2 z2 partial
  ushort* WkT = (ushort*)take(2097152);   // WkT||WvT contiguous = [2048][1024]
  ushort* WvT = (ushort*)take(2097152);
  ushort* WoT = (ushort*)take(2097152);
  ushort* WrT = (ushort*)take(2097152);
  ushort* W1T = (ushort*)take(8388608);   // dead after FFN1 -> FFN2 z3 partial
  ushort* W2T = (ushort*)take(8388608);

  char* regA = take(8388608);             // kvb + remb; later reused for fbuf
  ushort* kvb  = (ushort*)regA;
  ushort* remb = (ushort*)(regA + 5242880);
  float*  fbuf = (float*)regA;            // FFN2 z0 (+bias)

  char* regB = take(20185088);            // qb,kb,Vt,Rb,attb; overlays: o2b, g
  ushort* qb   = (ushort*)regB;
  ushort* kb   = (ushort*)(regB + 4194304);
  ushort* Vt   = (ushort*)(regB + 9437184);
  ushort* Rb   = (ushort*)(regB + 14680064);
  ushort* attb = (ushort*)(regB + 15990784);
  float*  o2b  = (float*)regB;            // Wo z=1 partial
  ushort* g    = (ushort*)regB;           // FFN1 out

  float*  o2 = (float*)take(8388608);     // Wo z0; later FFN2 z1 partial
  float*  h  = (float*)take(8388608);
  ushort* hb = (ushort*)take(4194304);

  float* p2 = (float*)WqT;                // FFN2 z2 partial
  float* p3 = (float*)W1T;                // FFN2 z3 partial

  prep_kernel<<<17152, 256, 0, stream>>>(x, mem, Wq, Wk, Wv, Wo, Wr, W1, W2,
                                         WqT, WkT, WvT, WoT, WrT, W1T, W2T, kvb, remb);

  proj8p<<<244, 512, 98304, stream>>>(kvb, WqT, WkT, WrT, remb, qb, kb, Vt, Rb);

  attn_mfma8<<<512, 256, 0, stream>>>(qb, kb, Vt, Rb, u, v, attb);

  // Wo: 8-phase SK2, 128 blocks (z0->o2, z1->o2b)
  gemm8p2_kern<1, 2><<<128, 512, 98304, stream>>>(attb, WoT, o2, o2b, nullptr, nullptr,
                                                  nullptr, 2048, 1024, 512, 1024, 4);
  ln_kernel<<<2048, 256, 0, stream>>>(x, o2, o2b, nullptr, nullptr, ln1g, ln1b, h, hb);

  // FFN1: 8-phase 128x256, 256 blocks (full chip)
  gemm8p2_kern<2, 1><<<256, 512, 98304, stream>>>(hb, W1T, g, nullptr, nullptr, nullptr,
                                                  b1, 2048, 4096, 1024, 1024, 16);

  // FFN2: 8-phase SK4, 256 blocks (z0->fbuf(+b2), z1->o2, z2->p2, z3->p3)
  gemm8p2_kern<3, 4><<<256, 512, 98304, stream>>>(g, W2T, fbuf, o2, p2, p3,
                                                  b2, 2048, 1024, 1024, 4096, 4);
  ln_kernel<<<2048, 256, 0, stream>>>(h, fbuf, o2, p2, p3, ln2g, ln2b, out, nullptr);
}